// Round 1
// baseline (405.539 us; speedup 1.0000x reference)
//
#include <hip/hip_runtime.h>
#include <stdint.h>

typedef uint16_t u16;
typedef uint32_t u32;
typedef __attribute__((ext_vector_type(8)))  __bf16 bf16x8;
typedef __attribute__((ext_vector_type(16))) float  f32x16;

#define NROWS   100000
#define E_EDGES 3200000

// LDS activation tile: H[128 rows][256 cols] bf16, XOR-swizzled on 8-elem (16B)
// granules: elem offset = row*256 + ((g ^ (row&31))<<3) + e   (g = col>>3)
#define HIDX(r, g) (((r) << 8) + ((((g) ^ ((r) & 31))) << 3))

#define MFMA(a, b, c) __builtin_amdgcn_mfma_f32_32x32x16_bf16((a), (b), (c), 0, 0, 0)

__device__ __forceinline__ u32 pk_bf16(float a, float b) {
    u32 ua = __builtin_bit_cast(u32, a), ub = __builtin_bit_cast(u32, b);
    ua = (ua + 0x7FFFu + ((ua >> 16) & 1u)) >> 16;   // RNE
    ub = (ub + 0x7FFFu + ((ub >> 16) & 1u)) >> 16;
    return ua | (ub << 16);
}
__device__ __forceinline__ float fast_tanh(float x) {
    float e = __expf(2.0f * x);                       // large |x| -> +-1 exactly
    return 1.0f - 2.0f / (e + 1.0f);
}
__device__ __forceinline__ float fast_sigmoid(float x) {
    return 1.0f / (1.0f + __expf(-x));
}

// stage 16 KB (8192 u16) global -> LDS, 4 rounds x 256 thr x 16B, async DMA
__device__ __forceinline__ void stage16k(u16* dst, const u16* src, int tid) {
#pragma unroll
    for (int q = 0; q < 4; ++q) {
        int n16 = q * 256 + tid;
        __builtin_amdgcn_global_load_lds(
            (const __attribute__((address_space(1))) void*)(const void*)(src + n16 * 8),
            (__attribute__((address_space(3))) void*)(void*)(dst + n16 * 8), 16, 0, 0);
    }
}

// One 256->256 dense layer + bias + tanh, H (LDS) -> H (LDS) in place.
// WB layout: [chunk 8][kstep 2][n 256][kloc 16] bf16 (k = c*32 + s*16 + kloc).
// Wave owns n-tiles {2w, 2w+1} x all 4 batch-tiles: acc[8] of 32x32.
__device__ __forceinline__ void dense256(u16* Hs, u16* Ws, const u16* WB,
                                         const float* bias, int tid, int wave, int lane) {
    const int l31 = lane & 31, lh = lane >> 5;
    f32x16 acc[8];
#pragma unroll
    for (int i = 0; i < 8; ++i)
#pragma unroll
        for (int j = 0; j < 16; ++j) acc[i][j] = 0.0f;

#pragma unroll 1
    for (int c = 0; c < 8; ++c) {
        __syncthreads();                      // prev compute done with Ws / H writes visible
        stage16k(Ws, WB + c * 8192, tid);
        __syncthreads();                      // staging drained (vmcnt flushed at barrier)
#pragma unroll
        for (int ks = 0; ks < 2; ++ks) {
            const int g = c * 4 + ks * 2 + lh;
            bf16x8 w0 = *(const bf16x8*)(Ws + ks * 4096 + (wave * 64 + l31) * 16 + lh * 8);
            bf16x8 w1 = *(const bf16x8*)(Ws + ks * 4096 + (wave * 64 + 32 + l31) * 16 + lh * 8);
            bf16x8 h0 = *(const bf16x8*)(Hs + HIDX(l31, g));
            bf16x8 h1 = *(const bf16x8*)(Hs + HIDX(32 + l31, g));
            bf16x8 h2 = *(const bf16x8*)(Hs + HIDX(64 + l31, g));
            bf16x8 h3 = *(const bf16x8*)(Hs + HIDX(96 + l31, g));
            acc[0] = MFMA(w0, h0, acc[0]);
            acc[1] = MFMA(w0, h1, acc[1]);
            acc[2] = MFMA(w0, h2, acc[2]);
            acc[3] = MFMA(w0, h3, acc[3]);
            acc[4] = MFMA(w1, h0, acc[4]);
            acc[5] = MFMA(w1, h1, acc[5]);
            acc[6] = MFMA(w1, h2, acc[6]);
            acc[7] = MFMA(w1, h3, acc[7]);
        }
    }
    __syncthreads();                          // everyone done reading H before overwrite
    // epilogue: bias + tanh + packed write-back (4 consecutive neurons per reg-quad)
#pragma unroll
    for (int i = 0; i < 2; ++i) {
        const int nt = wave * 2 + i;
#pragma unroll
        for (int rg = 0; rg < 4; ++rg) {
            const int ns = nt * 32 + rg * 8 + lh * 4;    // first neuron of this reg-quad
            const float4 bv = *(const float4*)(bias + ns);
#pragma unroll
            for (int b = 0; b < 4; ++b) {
                f32x16& A = acc[i * 4 + b];
                float x0 = fast_tanh(A[rg * 4 + 0] + bv.x);
                float x1 = fast_tanh(A[rg * 4 + 1] + bv.y);
                float x2 = fast_tanh(A[rg * 4 + 2] + bv.z);
                float x3 = fast_tanh(A[rg * 4 + 3] + bv.w);
                const int r = b * 32 + l31;              // batch row (C/D col)
                const int g = nt * 4 + rg;               // neuron granule
                uint2 v; v.x = pk_bf16(x0, x1); v.y = pk_bf16(x2, x3);
                *(uint2*)(Hs + (r << 8) + (((g) ^ (r & 31)) << 3) + lh * 4) = v;
            }
        }
    }
    // no trailing barrier: next layer's pre-staging barrier covers the hazard
}

// final 256 -> 32(padded) layer; whole 16 KB weight block staged at once.
// WBf layout: [chunk 8][kstep 2][n 32][kloc 16]. Each wave: one 32-row batch tile.
__device__ __forceinline__ f32x16 final_dense(const u16* Hs, u16* Ws, const u16* WBf,
                                              int tid, int wave, int lane) {
    const int l31 = lane & 31, lh = lane >> 5;
    __syncthreads();
    stage16k(Ws, WBf, tid);
    __syncthreads();
    f32x16 acc;
#pragma unroll
    for (int j = 0; j < 16; ++j) acc[j] = 0.0f;
#pragma unroll
    for (int c = 0; c < 8; ++c)
#pragma unroll
        for (int ks = 0; ks < 2; ++ks) {
            bf16x8 w = *(const bf16x8*)(Ws + (c * 2 + ks) * 512 + l31 * 16 + lh * 8);
            const int g = c * 4 + ks * 2 + lh;
            bf16x8 h = *(const bf16x8*)(Hs + HIDX(wave * 32 + l31, g));
            acc = MFMA(w, h, acc);
        }
    return acc;
}

__global__ __launch_bounds__(256, 2) void mlp1_kernel(
    const float* __restrict__ ea, const u16* __restrict__ WB1, const u16* __restrict__ WB13,
    const float* __restrict__ b0, const float* __restrict__ b1, const float* __restrict__ b2,
    const float* __restrict__ b3, u16* __restrict__ out1) {
    __shared__ u16 Hs[128 * 256];   // 64 KB
    __shared__ u16 Ws[8192];        // 16 KB  (total 80 KB -> 2 blocks/CU)
    const int tid = threadIdx.x, wave = tid >> 6, lane = tid & 63, blk = blockIdx.x;

    // stage A = edge_attr.reshape(100000,256): coalesced 32B/lane, cvt to bf16
#pragma unroll 1
    for (int i = 0; i < 16; ++i) {
        const int r = i * 8 + (tid >> 5);       // local row 0..127
        const int g = tid & 31;                 // granule 0..31
        const int rg_ = blk * 128 + r;
        if (rg_ < NROWS) {
            const float* p = ea + (size_t)rg_ * 256 + g * 8;
            float4 a0 = *(const float4*)p;
            float4 a1 = *(const float4*)(p + 4);
            uint4 v; v.x = pk_bf16(a0.x, a0.y); v.y = pk_bf16(a0.z, a0.w);
            v.z = pk_bf16(a1.x, a1.y); v.w = pk_bf16(a1.z, a1.w);
            *(uint4*)(Hs + HIDX(r, g)) = v;
        }
    }
    dense256(Hs, Ws, WB1,           b0, tid, wave, lane);
    dense256(Hs, Ws, WB1 + 65536,   b1, tid, wave, lane);
    dense256(Hs, Ws, WB1 + 131072,  b2, tid, wave, lane);
    f32x16 acc = final_dense(Hs, Ws, WB13, tid, wave, lane);

    const int row_g = blk * 128 + wave * 32 + (lane & 31);
    if (row_g < NROWS) {
        if ((lane >> 5) == 0) {  // neurons 0..3 in regs 0..3
            float s0 = fast_sigmoid(acc[0] + b3[0]);
            float s1 = fast_sigmoid(acc[1] + b3[1]);
            float s2 = fast_sigmoid(acc[2] + b3[2]);
            float s3 = fast_sigmoid(acc[3] + b3[3]);
            uint2 v; v.x = pk_bf16(s0, s1); v.y = pk_bf16(s2, s3);
            *(uint2*)(out1 + (size_t)row_g * 8) = v;
        } else {                 // neuron 4 in reg 0; zero-pad 5..7
            float s4 = fast_sigmoid(acc[0] + b3[4]);
            uint2 v; v.x = pk_bf16(s4, 0.0f); v.y = 0u;
            *(uint2*)(out1 + (size_t)row_g * 8 + 4) = v;
        }
    }
}

__global__ __launch_bounds__(256, 2) void mlp2_kernel(
    const int* __restrict__ idx1, const u16* __restrict__ out1,
    const u16* __restrict__ WB2, const u16* __restrict__ WB23,
    const float* __restrict__ b0, const float* __restrict__ b1, const float* __restrict__ b2,
    const float* __restrict__ b3, float* __restrict__ out) {
    __shared__ u16 Hs[128 * 256];
    __shared__ u16 Ws[8192];
    const int tid = threadIdx.x, wave = tid >> 6, lane = tid & 63, blk = blockIdx.x;

    // gather: H2[row][8j..8j+7] = out1_padded[idx[row*32+j]]  (one uint4 per node)
#pragma unroll 1
    for (int i = 0; i < 16; ++i) {
        const int li = i * 256 + tid;           // 0..4095
        const int r = li >> 5, j = li & 31;
        const long e = (long)blk * 4096 + li;
        if (e < (long)E_EDGES) {
            const int node = idx1[e];
            uint4 v = *(const uint4*)(out1 + (size_t)node * 8);
            *(uint4*)(Hs + HIDX(r, j)) = v;
        }
    }
    dense256(Hs, Ws, WB2,          b0, tid, wave, lane);   // K padded 160->256, zero weights
    dense256(Hs, Ws, WB2 + 65536,  b1, tid, wave, lane);
    dense256(Hs, Ws, WB2 + 131072, b2, tid, wave, lane);
    f32x16 acc = final_dense(Hs, Ws, WB23, tid, wave, lane);

    const int row_g = blk * 128 + wave * 32 + (lane & 31);
    if (row_g < NROWS && (lane >> 5) == 0)
        out[row_g] = fast_sigmoid(acc[0] + b3[0]);
}

// Build all bf16 blocked weight layouts in workspace (once per launch).
__global__ void transform_kernel(
    const float* __restrict__ w10, const float* __restrict__ w11, const float* __restrict__ w12,
    const float* __restrict__ w13, const float* __restrict__ w20, const float* __restrict__ w21,
    const float* __restrict__ w22, const float* __restrict__ w23, u16* __restrict__ ws) {
    const int id = blockIdx.x * 256 + threadIdx.x;   // 409600 outputs
    float val;
    if (id < 196608) {                         // WB1: 3 layers [8][2][256][16]
        int layer = id >> 16, rem = id & 65535;
        int c = rem >> 13, s = (rem >> 12) & 1, n = (rem >> 4) & 255, kl = rem & 15;
        int k = c * 32 + s * 16 + kl;
        const float* w = layer == 0 ? w10 : (layer == 1 ? w11 : w12);
        val = w[k * 256 + n];
    } else if (id < 204800) {                  // WB13: [8][2][32][16], n>=5 zero
        int rem = id - 196608;
        int c = rem >> 10, s = (rem >> 9) & 1, n = (rem >> 4) & 31, kl = rem & 15;
        int k = c * 32 + s * 16 + kl;
        val = (n < 5) ? w13[k * 5 + n] : 0.0f;
    } else if (id < 401408) {                  // WB2: 3 layers; layer0 K 160->256 expanded
        int rem = id - 204800;
        int layer = rem >> 16; rem &= 65535;
        int c = rem >> 13, s = (rem >> 12) & 1, n = (rem >> 4) & 255, kl = rem & 15;
        int k = c * 32 + s * 16 + kl;
        if (layer == 0) {
            int j = k >> 3, v = k & 7;
            val = (v < 5) ? w20[(j * 5 + v) * 256 + n] : 0.0f;
        } else {
            val = (layer == 1 ? w21 : w22)[k * 256 + n];
        }
    } else {                                   // WB23: [8][2][32][16], n!=0 zero
        int rem = id - 401408;
        int c = rem >> 10, s = (rem >> 9) & 1, n = (rem >> 4) & 31, kl = rem & 15;
        int k = c * 32 + s * 16 + kl;
        val = (n == 0) ? w23[k] : 0.0f;
    }
    u32 u = __builtin_bit_cast(u32, val);
    u = (u + 0x7FFFu + ((u >> 16) & 1u)) >> 16;
    ws[id] = (u16)u;
}

extern "C" void kernel_launch(void* const* d_in, const int* in_sizes, int n_in,
                              void* d_out, int out_size, void* d_ws, size_t ws_size,
                              hipStream_t stream) {
    const int*   ei  = (const int*)d_in[1];     // edge_index [2][E] int32
    const float* ea  = (const float*)d_in[2];   // edge_attr [E][8] f32
    const float* w10 = (const float*)d_in[3];  const float* b10 = (const float*)d_in[4];
    const float* w11 = (const float*)d_in[5];  const float* b11 = (const float*)d_in[6];
    const float* w12 = (const float*)d_in[7];  const float* b12 = (const float*)d_in[8];
    const float* w13 = (const float*)d_in[9];  const float* b13 = (const float*)d_in[10];
    const float* w20 = (const float*)d_in[11]; const float* b20 = (const float*)d_in[12];
    const float* w21 = (const float*)d_in[13]; const float* b21 = (const float*)d_in[14];
    const float* w22 = (const float*)d_in[15]; const float* b22 = (const float*)d_in[16];
    const float* w23 = (const float*)d_in[17]; const float* b23 = (const float*)d_in[18];

    u16* ws   = (u16*)d_ws;            // u16-unit offsets
    u16* WB1  = ws;                    // 196608
    u16* WB13 = ws + 196608;           // 8192
    u16* WB2  = ws + 204800;           // 196608
    u16* WB23 = ws + 401408;           // 8192
    u16* out1 = ws + 409600;           // 100000 x 8 bf16 (padded rows)

    hipLaunchKernelGGL(transform_kernel, dim3(1600), dim3(256), 0, stream,
                       w10, w11, w12, w13, w20, w21, w22, w23, ws);
    hipLaunchKernelGGL(mlp1_kernel, dim3(782), dim3(256), 0, stream,
                       ea, WB1, WB13, b10, b11, b12, b13, out1);
    hipLaunchKernelGGL(mlp2_kernel, dim3(782), dim3(256), 0, stream,
                       ei + E_EDGES, out1, WB2, WB23, b20, b21, b22, b23, (float*)d_out);
}

// Round 2
// 405.362 us; speedup vs baseline: 1.0004x; 1.0004x over previous
//
#include <hip/hip_runtime.h>
#include <stdint.h>

typedef uint16_t u16;
typedef uint32_t u32;
typedef __attribute__((ext_vector_type(8)))  __bf16 bf16x8;
typedef __attribute__((ext_vector_type(16))) float  f32x16;

#define NROWS   100000
#define E_EDGES 3200000

// LDS activation tile: H[128 rows][256 cols] bf16, XOR-swizzled on 8-elem (16B)
// granules: elem offset = row*256 + ((g ^ (row&31))<<3) + e   (g = col>>3)
#define HIDX(r, g) (((r) << 8) + ((((g) ^ ((r) & 31))) << 3))

#define MFMA(a, b, c) __builtin_amdgcn_mfma_f32_32x32x16_bf16((a), (b), (c), 0, 0, 0)

__device__ __forceinline__ u32 pk_bf16(float a, float b) {
    u32 ua = __builtin_bit_cast(u32, a), ub = __builtin_bit_cast(u32, b);
    ua = (ua + 0x7FFFu + ((ua >> 16) & 1u)) >> 16;   // RNE
    ub = (ub + 0x7FFFu + ((ub >> 16) & 1u)) >> 16;
    return ua | (ub << 16);
}
__device__ __forceinline__ float fast_tanh(float x) {
    float e = __expf(2.0f * x);                       // large |x| -> +-1 exactly
    return 1.0f - 2.0f / (e + 1.0f);
}
__device__ __forceinline__ float fast_sigmoid(float x) {
    return 1.0f / (1.0f + __expf(-x));
}

// One 256->256 dense layer + bias + tanh, H (LDS) -> H (LDS) in place.
// Weights load DIRECTLY global->VGPR (no LDS staging, no intra-layer barriers).
// WB layout: [chunk 8][kstep 2][n 256][kloc 16] bf16 (k = c*32 + s*16 + kloc):
// for fixed (c,ks) the wave's 64 lanes cover one contiguous 2 KB slab -> fully
// coalesced global_load_dwordx4, L2-resident after first blocks.
// Wave owns n-tiles {2w, 2w+1} x all 4 batch-tiles: acc[8] of 32x32.
__device__ __forceinline__ void dense256_reg(u16* Hs, const u16* __restrict__ WB,
                                             const float* __restrict__ bias,
                                             int wave, int lane) {
    const int l31 = lane & 31, lh = lane >> 5;
    f32x16 acc[8];
#pragma unroll
    for (int i = 0; i < 8; ++i)
#pragma unroll
        for (int j = 0; j < 16; ++j) acc[i][j] = 0.0f;

    __syncthreads();   // H writes from previous layer/staging visible

    const u16* wbase = WB + (wave * 64 + l31) * 16 + lh * 8;
#pragma unroll
    for (int c = 0; c < 8; ++c) {
#pragma unroll
        for (int ks = 0; ks < 2; ++ks) {
            const int g = c * 4 + ks * 2 + lh;
            bf16x8 w0 = *(const bf16x8*)(wbase + c * 8192 + ks * 4096);
            bf16x8 w1 = *(const bf16x8*)(wbase + c * 8192 + ks * 4096 + 512);  // +32 neurons
            bf16x8 h0 = *(const bf16x8*)(Hs + HIDX(l31, g));
            bf16x8 h1 = *(const bf16x8*)(Hs + HIDX(32 + l31, g));
            bf16x8 h2 = *(const bf16x8*)(Hs + HIDX(64 + l31, g));
            bf16x8 h3 = *(const bf16x8*)(Hs + HIDX(96 + l31, g));
            acc[0] = MFMA(w0, h0, acc[0]);
            acc[1] = MFMA(w0, h1, acc[1]);
            acc[2] = MFMA(w0, h2, acc[2]);
            acc[3] = MFMA(w0, h3, acc[3]);
            acc[4] = MFMA(w1, h0, acc[4]);
            acc[5] = MFMA(w1, h1, acc[5]);
            acc[6] = MFMA(w1, h2, acc[6]);
            acc[7] = MFMA(w1, h3, acc[7]);
        }
    }
    __syncthreads();   // all H reads done before in-place overwrite

    // epilogue: bias + tanh + packed write-back (4 consecutive neurons per reg-quad)
#pragma unroll
    for (int i = 0; i < 2; ++i) {
        const int nt = wave * 2 + i;
#pragma unroll
        for (int rg = 0; rg < 4; ++rg) {
            const int ns = nt * 32 + rg * 8 + lh * 4;    // first neuron of this reg-quad
            const float4 bv = *(const float4*)(bias + ns);
#pragma unroll
            for (int b = 0; b < 4; ++b) {
                f32x16& A = acc[i * 4 + b];
                float x0 = fast_tanh(A[rg * 4 + 0] + bv.x);
                float x1 = fast_tanh(A[rg * 4 + 1] + bv.y);
                float x2 = fast_tanh(A[rg * 4 + 2] + bv.z);
                float x3 = fast_tanh(A[rg * 4 + 3] + bv.w);
                const int r = b * 32 + l31;              // batch row (C/D col)
                const int g = nt * 4 + rg;               // neuron granule
                uint2 v; v.x = pk_bf16(x0, x1); v.y = pk_bf16(x2, x3);
                *(uint2*)(Hs + (r << 8) + (((g) ^ (r & 31)) << 3) + lh * 4) = v;
            }
        }
    }
    // no trailing barrier: next layer's entry barrier covers the hazard
}

// final 256 -> 32(padded) layer, weights global->VGPR (16 KB, L1/L2-hot).
// WBf layout: [chunk 8][kstep 2][n 32][kloc 16]. Each wave: one 32-row batch tile.
__device__ __forceinline__ f32x16 final_dense_reg(const u16* Hs, const u16* __restrict__ WBf,
                                                  int wave, int lane) {
    const int l31 = lane & 31, lh = lane >> 5;
    __syncthreads();   // H ready
    f32x16 acc;
#pragma unroll
    for (int j = 0; j < 16; ++j) acc[j] = 0.0f;
    const u16* wbase = WBf + l31 * 16 + lh * 8;
#pragma unroll
    for (int c = 0; c < 8; ++c)
#pragma unroll
        for (int ks = 0; ks < 2; ++ks) {
            bf16x8 w = *(const bf16x8*)(wbase + (c * 2 + ks) * 512);
            const int g = c * 4 + ks * 2 + lh;
            bf16x8 h = *(const bf16x8*)(Hs + HIDX(wave * 32 + l31, g));
            acc = MFMA(w, h, acc);
        }
    return acc;
}

__global__ __launch_bounds__(256, 2) void mlp1_kernel(
    const float* __restrict__ ea, const u16* __restrict__ WB1, const u16* __restrict__ WB13,
    const float* __restrict__ b0, const float* __restrict__ b1, const float* __restrict__ b2,
    const float* __restrict__ b3, u16* __restrict__ out1) {
    __shared__ u16 Hs[128 * 256];   // 64 KB -> 2 blocks/CU
    const int tid = threadIdx.x, wave = tid >> 6, lane = tid & 63, blk = blockIdx.x;

    // stage A = edge_attr.reshape(100000,256): coalesced 32B/lane, cvt to bf16
#pragma unroll 1
    for (int i = 0; i < 16; ++i) {
        const int r = i * 8 + (tid >> 5);       // local row 0..127
        const int g = tid & 31;                 // granule 0..31
        const int rg_ = blk * 128 + r;
        if (rg_ < NROWS) {
            const float* p = ea + (size_t)rg_ * 256 + g * 8;
            float4 a0 = *(const float4*)p;
            float4 a1 = *(const float4*)(p + 4);
            uint4 v; v.x = pk_bf16(a0.x, a0.y); v.y = pk_bf16(a0.z, a0.w);
            v.z = pk_bf16(a1.x, a1.y); v.w = pk_bf16(a1.z, a1.w);
            *(uint4*)(Hs + HIDX(r, g)) = v;
        }
    }
    dense256_reg(Hs, WB1,          b0, wave, lane);
    dense256_reg(Hs, WB1 + 65536,  b1, wave, lane);
    dense256_reg(Hs, WB1 + 131072, b2, wave, lane);
    f32x16 acc = final_dense_reg(Hs, WB13, wave, lane);

    const int row_g = blk * 128 + wave * 32 + (lane & 31);
    if (row_g < NROWS) {
        if ((lane >> 5) == 0) {  // neurons 0..3 in regs 0..3
            float s0 = fast_sigmoid(acc[0] + b3[0]);
            float s1 = fast_sigmoid(acc[1] + b3[1]);
            float s2 = fast_sigmoid(acc[2] + b3[2]);
            float s3 = fast_sigmoid(acc[3] + b3[3]);
            uint2 v; v.x = pk_bf16(s0, s1); v.y = pk_bf16(s2, s3);
            *(uint2*)(out1 + (size_t)row_g * 8) = v;
        } else {                 // neuron 4 in reg 0; zero-pad 5..7
            float s4 = fast_sigmoid(acc[0] + b3[4]);
            uint2 v; v.x = pk_bf16(s4, 0.0f); v.y = 0u;
            *(uint2*)(out1 + (size_t)row_g * 8 + 4) = v;
        }
    }
}

__global__ __launch_bounds__(256, 2) void mlp2_kernel(
    const int* __restrict__ idx1, const u16* __restrict__ out1,
    const u16* __restrict__ WB2, const u16* __restrict__ WB23,
    const float* __restrict__ b0, const float* __restrict__ b1, const float* __restrict__ b2,
    const float* __restrict__ b3, float* __restrict__ out) {
    __shared__ u16 Hs[128 * 256];
    const int tid = threadIdx.x, wave = tid >> 6, lane = tid & 63, blk = blockIdx.x;

    // gather: H2[row][8j..8j+7] = out1_padded[idx[row*32+j]]  (one uint4 per node)
#pragma unroll 1
    for (int i = 0; i < 16; ++i) {
        const int li = i * 256 + tid;           // 0..4095
        const int r = li >> 5, j = li & 31;
        const long e = (long)blk * 4096 + li;
        if (e < (long)E_EDGES) {
            const int node = idx1[e];
            uint4 v = *(const uint4*)(out1 + (size_t)node * 8);
            *(uint4*)(Hs + HIDX(r, j)) = v;
        }
    }
    dense256_reg(Hs, WB2,          b0, wave, lane);   // K padded 160->256, zero weights
    dense256_reg(Hs, WB2 + 65536,  b1, wave, lane);
    dense256_reg(Hs, WB2 + 131072, b2, wave, lane);
    f32x16 acc = final_dense_reg(Hs, WB23, wave, lane);

    const int row_g = blk * 128 + wave * 32 + (lane & 31);
    if (row_g < NROWS && (lane >> 5) == 0)
        out[row_g] = fast_sigmoid(acc[0] + b3[0]);
}

// Build all bf16 blocked weight layouts in workspace (once per launch).
__global__ void transform_kernel(
    const float* __restrict__ w10, const float* __restrict__ w11, const float* __restrict__ w12,
    const float* __restrict__ w13, const float* __restrict__ w20, const float* __restrict__ w21,
    const float* __restrict__ w22, const float* __restrict__ w23, u16* __restrict__ ws) {
    const int id = blockIdx.x * 256 + threadIdx.x;   // 409600 outputs
    float val;
    if (id < 196608) {                         // WB1: 3 layers [8][2][256][16]
        int layer = id >> 16, rem = id & 65535;
        int c = rem >> 13, s = (rem >> 12) & 1, n = (rem >> 4) & 255, kl = rem & 15;
        int k = c * 32 + s * 16 + kl;
        const float* w = layer == 0 ? w10 : (layer == 1 ? w11 : w12);
        val = w[k * 256 + n];
    } else if (id < 204800) {                  // WB13: [8][2][32][16], n>=5 zero
        int rem = id - 196608;
        int c = rem >> 10, s = (rem >> 9) & 1, n = (rem >> 4) & 31, kl = rem & 15;
        int k = c * 32 + s * 16 + kl;
        val = (n < 5) ? w13[k * 5 + n] : 0.0f;
    } else if (id < 401408) {                  // WB2: 3 layers; layer0 K 160->256 expanded
        int rem = id - 204800;
        int layer = rem >> 16; rem &= 65535;
        int c = rem >> 13, s = (rem >> 12) & 1, n = (rem >> 4) & 255, kl = rem & 15;
        int k = c * 32 + s * 16 + kl;
        if (layer == 0) {
            int j = k >> 3, v = k & 7;
            val = (v < 5) ? w20[(j * 5 + v) * 256 + n] : 0.0f;
        } else {
            val = (layer == 1 ? w21 : w22)[k * 256 + n];
        }
    } else {                                   // WB23: [8][2][32][16], n!=0 zero
        int rem = id - 401408;
        int c = rem >> 10, s = (rem >> 9) & 1, n = (rem >> 4) & 31, kl = rem & 15;
        int k = c * 32 + s * 16 + kl;
        val = (n == 0) ? w23[k] : 0.0f;
    }
    u32 u = __builtin_bit_cast(u32, val);
    u = (u + 0x7FFFu + ((u >> 16) & 1u)) >> 16;
    ws[id] = (u16)u;
}

extern "C" void kernel_launch(void* const* d_in, const int* in_sizes, int n_in,
                              void* d_out, int out_size, void* d_ws, size_t ws_size,
                              hipStream_t stream) {
    const int*   ei  = (const int*)d_in[1];     // edge_index [2][E] int32
    const float* ea  = (const float*)d_in[2];   // edge_attr [E][8] f32
    const float* w10 = (const float*)d_in[3];  const float* b10 = (const float*)d_in[4];
    const float* w11 = (const float*)d_in[5];  const float* b11 = (const float*)d_in[6];
    const float* w12 = (const float*)d_in[7];  const float* b12 = (const float*)d_in[8];
    const float* w13 = (const float*)d_in[9];  const float* b13 = (const float*)d_in[10];
    const float* w20 = (const float*)d_in[11]; const float* b20 = (const float*)d_in[12];
    const float* w21 = (const float*)d_in[13]; const float* b21 = (const float*)d_in[14];
    const float* w22 = (const float*)d_in[15]; const float* b22 = (const float*)d_in[16];
    const float* w23 = (const float*)d_in[17]; const float* b23 = (const float*)d_in[18];

    u16* ws   = (u16*)d_ws;            // u16-unit offsets
    u16* WB1  = ws;                    // 196608
    u16* WB13 = ws + 196608;           // 8192
    u16* WB2  = ws + 204800;           // 196608
    u16* WB23 = ws + 401408;           // 8192
    u16* out1 = ws + 409600;           // 100000 x 8 bf16 (padded rows)

    hipLaunchKernelGGL(transform_kernel, dim3(1600), dim3(256), 0, stream,
                       w10, w11, w12, w13, w20, w21, w22, w23, ws);
    hipLaunchKernelGGL(mlp1_kernel, dim3(782), dim3(256), 0, stream,
                       ea, WB1, WB13, b10, b11, b12, b13, out1);
    hipLaunchKernelGGL(mlp2_kernel, dim3(782), dim3(256), 0, stream,
                       ei + E_EDGES, out1, WB2, WB23, b20, b21, b22, b23, (float*)d_out);
}

// Round 3
// 396.010 us; speedup vs baseline: 1.0241x; 1.0236x over previous
//
#include <hip/hip_runtime.h>
#include <stdint.h>

typedef uint16_t u16;
typedef uint32_t u32;
typedef __attribute__((ext_vector_type(8)))  __bf16 bf16x8;
typedef __attribute__((ext_vector_type(16))) float  f32x16;

#define NROWS   100000
#define E_EDGES 3200000

// LDS activation tile: H[128 rows][256 cols] bf16, XOR-swizzled on 8-elem (16B)
// granules: elem offset = row*256 + ((g ^ (row&31))<<3) + e   (g = col>>3)
#define HIDX(r, g) (((r) << 8) + ((((g) ^ ((r) & 31))) << 3))

#define MFMA(a, b, c) __builtin_amdgcn_mfma_f32_32x32x16_bf16((a), (b), (c), 0, 0, 0)

__device__ __forceinline__ u32 pk_bf16(float a, float b) {
    u32 ua = __builtin_bit_cast(u32, a), ub = __builtin_bit_cast(u32, b);
    ua = (ua + 0x7FFFu + ((ua >> 16) & 1u)) >> 16;   // RNE
    ub = (ub + 0x7FFFu + ((ub >> 16) & 1u)) >> 16;
    return ua | (ub << 16);
}
// rcp-based (no precise-div sequence): ~1e-7 rel err, far under bf16 noise
__device__ __forceinline__ float fast_tanh(float x) {
    float e = __expf(2.0f * x);
    return 1.0f - __fdividef(2.0f, e + 1.0f);
}
__device__ __forceinline__ float fast_sigmoid(float x) {
    return __fdividef(1.0f, 1.0f + __expf(-x));
}

// One 256->256 dense layer + bias + tanh, H (LDS) -> H (LDS) in place.
// 8 waves/block; wave owns n-tiles {2(w&3), +1} x batch-tiles {2(w>>2), +1}:
// 4 acc tiles = 64 AGPRs. Weights global->VGPR (L2-resident), coalesced 2KB slabs.
__device__ __forceinline__ void dense256_reg(u16* Hs, const u16* __restrict__ WB,
                                             const float* __restrict__ bias,
                                             int wave, int lane) {
    const int l31 = lane & 31, lh = lane >> 5;
    const int nt0 = (wave & 3) * 2;          // first of 2 neuron tiles
    const int bb  = (wave >> 2) * 2;         // first of 2 batch tiles
    const int rb0 = bb * 32 + l31, rb1 = rb0 + 32;

    f32x16 acc[4];
#pragma unroll
    for (int i = 0; i < 4; ++i)
#pragma unroll
        for (int j = 0; j < 16; ++j) acc[i][j] = 0.0f;

    __syncthreads();   // H writes from previous layer/staging visible

    const u16* wbase = WB + (nt0 * 32 + l31) * 16 + lh * 8;   // +512 -> next n-tile
#pragma unroll
    for (int c = 0; c < 8; ++c) {
#pragma unroll
        for (int ks = 0; ks < 2; ++ks) {
            const int g = c * 4 + ks * 2 + lh;
            bf16x8 w0 = *(const bf16x8*)(wbase + c * 8192 + ks * 4096);
            bf16x8 w1 = *(const bf16x8*)(wbase + c * 8192 + ks * 4096 + 512);
            bf16x8 h0 = *(const bf16x8*)(Hs + HIDX(rb0, g));
            bf16x8 h1 = *(const bf16x8*)(Hs + HIDX(rb1, g));
            acc[0] = MFMA(w0, h0, acc[0]);
            acc[1] = MFMA(w0, h1, acc[1]);
            acc[2] = MFMA(w1, h0, acc[2]);
            acc[3] = MFMA(w1, h1, acc[3]);
        }
    }
    __syncthreads();   // all H reads done before in-place overwrite

    // epilogue: bias + tanh + packed write-back (4 consecutive neurons per reg-quad)
#pragma unroll
    for (int i = 0; i < 2; ++i) {
        const int nt = nt0 + i;
#pragma unroll
        for (int rg = 0; rg < 4; ++rg) {
            const int ns = nt * 32 + rg * 8 + lh * 4;
            const float4 bv = *(const float4*)(bias + ns);
#pragma unroll
            for (int b = 0; b < 2; ++b) {
                f32x16& A = acc[i * 2 + b];
                float x0 = fast_tanh(A[rg * 4 + 0] + bv.x);
                float x1 = fast_tanh(A[rg * 4 + 1] + bv.y);
                float x2 = fast_tanh(A[rg * 4 + 2] + bv.z);
                float x3 = fast_tanh(A[rg * 4 + 3] + bv.w);
                const int r = (bb + b) * 32 + l31;       // batch row (C/D col)
                const int g = nt * 4 + rg;               // neuron granule
                uint2 v; v.x = pk_bf16(x0, x1); v.y = pk_bf16(x2, x3);
                *(uint2*)(Hs + (r << 8) + (((g) ^ (r & 31)) << 3) + lh * 4) = v;
            }
        }
    }
    // no trailing barrier: next layer's entry barrier covers the hazard
}

// final 256 -> 32(padded) layer; waves 0..3 each take one 32-row batch tile,
// waves 4..7 idle after the barrier (final layer is ~5% of the MFMA work).
__device__ __forceinline__ f32x16 final_dense_reg(const u16* Hs, const u16* __restrict__ WBf,
                                                  int wave, int lane) {
    const int l31 = lane & 31, lh = lane >> 5;
    __syncthreads();   // H ready
    f32x16 acc;
#pragma unroll
    for (int j = 0; j < 16; ++j) acc[j] = 0.0f;
    if (wave < 4) {
        const u16* wbase = WBf + l31 * 16 + lh * 8;
#pragma unroll
        for (int c = 0; c < 8; ++c)
#pragma unroll
            for (int ks = 0; ks < 2; ++ks) {
                bf16x8 w = *(const bf16x8*)(wbase + (c * 2 + ks) * 512);
                const int g = c * 4 + ks * 2 + lh;
                bf16x8 h = *(const bf16x8*)(Hs + HIDX(wave * 32 + l31, g));
                acc = MFMA(w, h, acc);
            }
    }
    return acc;
}

__global__ __launch_bounds__(512, 4) void mlp1_kernel(
    const float* __restrict__ ea, const u16* __restrict__ WB1, const u16* __restrict__ WB13,
    const float* __restrict__ b0, const float* __restrict__ b1, const float* __restrict__ b2,
    const float* __restrict__ b3, u16* __restrict__ out1) {
    __shared__ u16 Hs[128 * 256];   // 64 KB; 2 blocks/CU -> 16 waves/CU
    const int tid = threadIdx.x, wave = tid >> 6, lane = tid & 63, blk = blockIdx.x;

    // stage A = edge_attr.reshape(100000,256): coalesced 32B/lane, cvt to bf16
#pragma unroll
    for (int i = 0; i < 8; ++i) {
        const int r = i * 16 + (tid >> 5);      // local row 0..127
        const int g = tid & 31;                 // granule 0..31
        const int rg_ = blk * 128 + r;
        if (rg_ < NROWS) {
            const float* p = ea + (size_t)rg_ * 256 + g * 8;
            float4 a0 = *(const float4*)p;
            float4 a1 = *(const float4*)(p + 4);
            uint4 v; v.x = pk_bf16(a0.x, a0.y); v.y = pk_bf16(a0.z, a0.w);
            v.z = pk_bf16(a1.x, a1.y); v.w = pk_bf16(a1.z, a1.w);
            *(uint4*)(Hs + HIDX(r, g)) = v;
        }
    }
    dense256_reg(Hs, WB1,          b0, wave, lane);
    dense256_reg(Hs, WB1 + 65536,  b1, wave, lane);
    dense256_reg(Hs, WB1 + 131072, b2, wave, lane);
    f32x16 acc = final_dense_reg(Hs, WB13, wave, lane);

    if (wave < 4) {
        const int row_g = blk * 128 + wave * 32 + (lane & 31);
        if (row_g < NROWS) {
            if ((lane >> 5) == 0) {  // neurons 0..3 in regs 0..3
                float s0 = fast_sigmoid(acc[0] + b3[0]);
                float s1 = fast_sigmoid(acc[1] + b3[1]);
                float s2 = fast_sigmoid(acc[2] + b3[2]);
                float s3 = fast_sigmoid(acc[3] + b3[3]);
                uint2 v; v.x = pk_bf16(s0, s1); v.y = pk_bf16(s2, s3);
                *(uint2*)(out1 + (size_t)row_g * 8) = v;
            } else {                 // neuron 4 in reg 0; zero-pad 5..7
                float s4 = fast_sigmoid(acc[0] + b3[4]);
                uint2 v; v.x = pk_bf16(s4, 0.0f); v.y = 0u;
                *(uint2*)(out1 + (size_t)row_g * 8 + 4) = v;
            }
        }
    }
}

__global__ __launch_bounds__(512, 4) void mlp2_kernel(
    const int* __restrict__ idx1, const u16* __restrict__ out1,
    const u16* __restrict__ WB2, const u16* __restrict__ WB23,
    const float* __restrict__ b0, const float* __restrict__ b1, const float* __restrict__ b2,
    const float* __restrict__ b3, float* __restrict__ out) {
    __shared__ u16 Hs[128 * 256];
    const int tid = threadIdx.x, wave = tid >> 6, lane = tid & 63, blk = blockIdx.x;

    // gather: H2[row][8j..8j+7] = out1_padded[idx[row*32+j]]; prefetch all 8
    // indices, then keep 8 random 16B gathers in flight per thread.
    int nodes[8];
#pragma unroll
    for (int i = 0; i < 8; ++i) {
        const long e = (long)blk * 4096 + i * 512 + tid;
        nodes[i] = (e < (long)E_EDGES) ? idx1[e] : 0;
    }
#pragma unroll
    for (int i = 0; i < 8; ++i) {
        const int li = i * 512 + tid;           // 0..4095
        const int r = li >> 5, j = li & 31;
        const long e = (long)blk * 4096 + li;
        if (e < (long)E_EDGES) {
            uint4 v = *(const uint4*)(out1 + (size_t)nodes[i] * 8);
            *(uint4*)(Hs + HIDX(r, j)) = v;
        }
    }
    dense256_reg(Hs, WB2,          b0, wave, lane);   // K padded 160->256, zero weights
    dense256_reg(Hs, WB2 + 65536,  b1, wave, lane);
    dense256_reg(Hs, WB2 + 131072, b2, wave, lane);
    f32x16 acc = final_dense_reg(Hs, WB23, wave, lane);

    if (wave < 4) {
        const int row_g = blk * 128 + wave * 32 + (lane & 31);
        if (row_g < NROWS && (lane >> 5) == 0)
            out[row_g] = fast_sigmoid(acc[0] + b3[0]);
    }
}

// Build all bf16 blocked weight layouts in workspace (once per launch).
__global__ void transform_kernel(
    const float* __restrict__ w10, const float* __restrict__ w11, const float* __restrict__ w12,
    const float* __restrict__ w13, const float* __restrict__ w20, const float* __restrict__ w21,
    const float* __restrict__ w22, const float* __restrict__ w23, u16* __restrict__ ws) {
    const int id = blockIdx.x * 256 + threadIdx.x;   // 409600 outputs
    float val;
    if (id < 196608) {                         // WB1: 3 layers [8][2][256][16]
        int layer = id >> 16, rem = id & 65535;
        int c = rem >> 13, s = (rem >> 12) & 1, n = (rem >> 4) & 255, kl = rem & 15;
        int k = c * 32 + s * 16 + kl;
        const float* w = layer == 0 ? w10 : (layer == 1 ? w11 : w12);
        val = w[k * 256 + n];
    } else if (id < 204800) {                  // WB13: [8][2][32][16], n>=5 zero
        int rem = id - 196608;
        int c = rem >> 10, s = (rem >> 9) & 1, n = (rem >> 4) & 31, kl = rem & 15;
        int k = c * 32 + s * 16 + kl;
        val = (n < 5) ? w13[k * 5 + n] : 0.0f;
    } else if (id < 401408) {                  // WB2: 3 layers; layer0 K 160->256 expanded
        int rem = id - 204800;
        int layer = rem >> 16; rem &= 65535;
        int c = rem >> 13, s = (rem >> 12) & 1, n = (rem >> 4) & 255, kl = rem & 15;
        int k = c * 32 + s * 16 + kl;
        if (layer == 0) {
            int j = k >> 3, v = k & 7;
            val = (v < 5) ? w20[(j * 5 + v) * 256 + n] : 0.0f;
        } else {
            val = (layer == 1 ? w21 : w22)[k * 256 + n];
        }
    } else {                                   // WB23: [8][2][32][16], n!=0 zero
        int rem = id - 401408;
        int c = rem >> 10, s = (rem >> 9) & 1, n = (rem >> 4) & 31, kl = rem & 15;
        int k = c * 32 + s * 16 + kl;
        val = (n == 0) ? w23[k] : 0.0f;
    }
    u32 u = __builtin_bit_cast(u32, val);
    u = (u + 0x7FFFu + ((u >> 16) & 1u)) >> 16;
    ws[id] = (u16)u;
}

extern "C" void kernel_launch(void* const* d_in, const int* in_sizes, int n_in,
                              void* d_out, int out_size, void* d_ws, size_t ws_size,
                              hipStream_t stream) {
    const int*   ei  = (const int*)d_in[1];     // edge_index [2][E] int32
    const float* ea  = (const float*)d_in[2];   // edge_attr [E][8] f32
    const float* w10 = (const float*)d_in[3];  const float* b10 = (const float*)d_in[4];
    const float* w11 = (const float*)d_in[5];  const float* b11 = (const float*)d_in[6];
    const float* w12 = (const float*)d_in[7];  const float* b12 = (const float*)d_in[8];
    const float* w13 = (const float*)d_in[9];  const float* b13 = (const float*)d_in[10];
    const float* w20 = (const float*)d_in[11]; const float* b20 = (const float*)d_in[12];
    const float* w21 = (const float*)d_in[13]; const float* b21 = (const float*)d_in[14];
    const float* w22 = (const float*)d_in[15]; const float* b22 = (const float*)d_in[16];
    const float* w23 = (const float*)d_in[17]; const float* b23 = (const float*)d_in[18];

    u16* ws   = (u16*)d_ws;            // u16-unit offsets
    u16* WB1  = ws;                    // 196608
    u16* WB13 = ws + 196608;           // 8192
    u16* WB2  = ws + 204800;           // 196608
    u16* WB23 = ws + 401408;           // 8192
    u16* out1 = ws + 409600;           // 100000 x 8 bf16 (padded rows)

    hipLaunchKernelGGL(transform_kernel, dim3(1600), dim3(256), 0, stream,
                       w10, w11, w12, w13, w20, w21, w22, w23, ws);
    hipLaunchKernelGGL(mlp1_kernel, dim3(782), dim3(512), 0, stream,
                       ea, WB1, WB13, b10, b11, b12, b13, out1);
    hipLaunchKernelGGL(mlp2_kernel, dim3(782), dim3(512), 0, stream,
                       ei + E_EDGES, out1, WB2, WB23, b20, b21, b22, b23, (float*)d_out);
}

// Round 4
// 364.150 us; speedup vs baseline: 1.1137x; 1.0875x over previous
//
#include <hip/hip_runtime.h>
#include <stdint.h>

typedef uint16_t u16;
typedef uint32_t u32;
typedef __attribute__((ext_vector_type(8)))  __bf16 bf16x8;
typedef __attribute__((ext_vector_type(16))) float  f32x16;

#define NROWS   100000
#define E_EDGES 3200000

// LDS activation tile: H[64 rows][256 cols] bf16, XOR-swizzled on 8-elem (16B)
// granules: elem offset = row*256 + ((g ^ (row&31))<<3) + e   (g = col>>3)
#define HIDX(r, g) (((r) << 8) + ((((g) ^ ((r) & 31))) << 3))

#define MFMA(a, b, c) __builtin_amdgcn_mfma_f32_32x32x16_bf16((a), (b), (c), 0, 0, 0)

__device__ __forceinline__ u32 pk_bf16(float a, float b) {
    u32 ua = __builtin_bit_cast(u32, a), ub = __builtin_bit_cast(u32, b);
    ua = (ua + 0x7FFFu + ((ua >> 16) & 1u)) >> 16;   // RNE
    ub = (ub + 0x7FFFu + ((ub >> 16) & 1u)) >> 16;
    return ua | (ub << 16);
}
__device__ __forceinline__ float fast_tanh(float x) {
    float e = __expf(2.0f * x);
    return 1.0f - __fdividef(2.0f, e + 1.0f);
}
__device__ __forceinline__ float fast_sigmoid(float x) {
    return __fdividef(1.0f, 1.0f + __expf(-x));
}

// Issue a full 16-slab weight load (64 VGPRs worth) for one n-tile.
__device__ __forceinline__ void load_w16(bf16x8 (&W)[16], const u16* __restrict__ base,
                                         int stride) {
#pragma unroll
    for (int s = 0; s < 16; ++s) W[s] = *(const bf16x8*)(base + s * stride);
}

// One 256->256 layer, Hin -> Hout (separate buffers, no intra-layer barrier).
// Wave owns n-tile `nt` for both 32-row batch tiles: acc = 2 x f32x16 (32 AGPR).
// Weights are register-resident (W[16]); step s ring-prefetches next layer's
// slab s into W[s] right after its last use -> barrier phases have no
// dependent global loads (loads stay in flight across epilogue + barrier).
__device__ __forceinline__ void dense_layer(const u16* __restrict__ Hin, u16* __restrict__ Hout,
                                            bf16x8 (&W)[16], const u16* __restrict__ pfbase,
                                            int pfstride, const float* __restrict__ bias,
                                            int nt, int l31, int lh) {
    f32x16 acc0, acc1;
#pragma unroll
    for (int j = 0; j < 16; ++j) { acc0[j] = 0.0f; acc1[j] = 0.0f; }

#pragma unroll
    for (int s = 0; s < 16; ++s) {
        const int g = 2 * s + lh;
        bf16x8 h0 = *(const bf16x8*)(Hin + HIDX(l31, g));
        bf16x8 h1 = *(const bf16x8*)(Hin + HIDX(32 + l31, g));
        acc0 = MFMA(W[s], h0, acc0);
        acc1 = MFMA(W[s], h1, acc1);
        W[s] = *(const bf16x8*)(pfbase + s * pfstride);   // prefetch next layer
    }
    // epilogue: bias + tanh + packed write to Hout (4 consecutive neurons/reg-quad)
#pragma unroll
    for (int rg = 0; rg < 4; ++rg) {
        const float4 bv = *(const float4*)(bias + nt * 32 + rg * 8 + lh * 4);
#pragma unroll
        for (int b = 0; b < 2; ++b) {
            const f32x16& A = b ? acc1 : acc0;
            float x0 = fast_tanh(A[rg * 4 + 0] + bv.x);
            float x1 = fast_tanh(A[rg * 4 + 1] + bv.y);
            float x2 = fast_tanh(A[rg * 4 + 2] + bv.z);
            float x3 = fast_tanh(A[rg * 4 + 3] + bv.w);
            const int r = b * 32 + l31;              // batch row (C/D col)
            const int g = nt * 4 + rg;               // neuron granule
            uint2 v; v.x = pk_bf16(x0, x1); v.y = pk_bf16(x2, x3);
            *(uint2*)(Hout + (r << 8) + (((g) ^ (r & 31)) << 3) + lh * 4) = v;
        }
    }
}

// final 256->32(padded) layer from Hin; waves 0..1 each take one 32-row tile.
// W already holds the final slab (prefetched by the previous dense_layer).
__device__ __forceinline__ f32x16 final_dense(const u16* __restrict__ Hin, bf16x8 (&W)[16],
                                              int wave, int l31, int lh) {
    f32x16 acc;
#pragma unroll
    for (int j = 0; j < 16; ++j) acc[j] = 0.0f;
    if (wave < 2) {
#pragma unroll
        for (int s = 0; s < 16; ++s) {
            const int g = 2 * s + lh;
            bf16x8 h = *(const bf16x8*)(Hin + HIDX(wave * 32 + l31, g));
            acc = MFMA(W[s], h, acc);
        }
    }
    return acc;
}

__global__ __launch_bounds__(512, 4) void mlp1_kernel(
    const float* __restrict__ ea, const u16* __restrict__ WB1, const u16* __restrict__ WB13,
    const float* __restrict__ b0, const float* __restrict__ b1, const float* __restrict__ b2,
    const float* __restrict__ b3, u16* __restrict__ out1) {
    __shared__ u16 H0[64 * 256];   // 32 KB
    __shared__ u16 H1[64 * 256];   // 32 KB  -> 64 KB total, 2 blocks/CU
    const int tid = threadIdx.x, wave = tid >> 6, lane = tid & 63, blk = blockIdx.x;
    const int l31 = lane & 31, lh = lane >> 5, nt = wave;
    const int woff = (nt * 32 + l31) * 16 + lh * 8;

    // issue layer-0 weight loads first (64 VGPRs, in flight during staging)
    bf16x8 W[16];
    load_w16(W, WB1 + woff, 4096);

    // stage A = edge_attr rows: coalesced 32B/lane, cvt to bf16 (zero-pad tail)
#pragma unroll
    for (int i = 0; i < 4; ++i) {
        const int r = i * 16 + (tid >> 5);      // local row 0..63
        const int g = tid & 31;                 // granule 0..31
        const int rg_ = blk * 64 + r;
        uint4 v = {0u, 0u, 0u, 0u};
        if (rg_ < NROWS) {
            const float* p = ea + (size_t)rg_ * 256 + g * 8;
            float4 a0 = *(const float4*)p;
            float4 a1 = *(const float4*)(p + 4);
            v.x = pk_bf16(a0.x, a0.y); v.y = pk_bf16(a0.z, a0.w);
            v.z = pk_bf16(a1.x, a1.y); v.w = pk_bf16(a1.z, a1.w);
        }
        *(uint4*)(H0 + HIDX(r, g)) = v;
    }
    __syncthreads();
    dense_layer(H0, H1, W, WB1 + 65536  + woff, 4096, b0, nt, l31, lh);
    __syncthreads();
    dense_layer(H1, H0, W, WB1 + 131072 + woff, 4096, b1, nt, l31, lh);
    __syncthreads();
    dense_layer(H0, H1, W, WB13 + l31 * 16 + lh * 8, 512, b2, nt, l31, lh);
    __syncthreads();
    f32x16 acc = final_dense(H1, W, wave, l31, lh);

    if (wave < 2) {
        const int row_g = blk * 64 + wave * 32 + l31;
        if (row_g < NROWS) {
            if (lh == 0) {           // neurons 0..3 in regs 0..3
                float s0 = fast_sigmoid(acc[0] + b3[0]);
                float s1 = fast_sigmoid(acc[1] + b3[1]);
                float s2 = fast_sigmoid(acc[2] + b3[2]);
                float s3 = fast_sigmoid(acc[3] + b3[3]);
                uint2 v; v.x = pk_bf16(s0, s1); v.y = pk_bf16(s2, s3);
                *(uint2*)(out1 + (size_t)row_g * 8) = v;
            } else {                 // neuron 4 in reg 0; zero-pad 5..7
                float s4 = fast_sigmoid(acc[0] + b3[4]);
                uint2 v; v.x = pk_bf16(s4, 0.0f); v.y = 0u;
                *(uint2*)(out1 + (size_t)row_g * 8 + 4) = v;
            }
        }
    }
}

__global__ __launch_bounds__(512, 4) void mlp2_kernel(
    const int* __restrict__ idx1, const u16* __restrict__ out1,
    const u16* __restrict__ WB2, const u16* __restrict__ WB23,
    const float* __restrict__ b0, const float* __restrict__ b1, const float* __restrict__ b2,
    const float* __restrict__ b3, float* __restrict__ out) {
    __shared__ u16 H0[64 * 256];
    __shared__ u16 H1[64 * 256];
    const int tid = threadIdx.x, wave = tid >> 6, lane = tid & 63, blk = blockIdx.x;
    const int l31 = lane & 31, lh = lane >> 5, nt = wave;
    const int woff = (nt * 32 + l31) * 16 + lh * 8;

    bf16x8 W[16];
    load_w16(W, WB2 + woff, 4096);

    // gather: 2048 nodes/block; prefetch indices then keep 4 gathers in flight
    int nodes[4];
#pragma unroll
    for (int i = 0; i < 4; ++i) {
        const long e = (long)blk * 2048 + i * 512 + tid;
        nodes[i] = (e < (long)E_EDGES) ? idx1[e] : -1;
    }
#pragma unroll
    for (int i = 0; i < 4; ++i) {
        const int li = i * 512 + tid;           // 0..2047
        const int r = li >> 5, j = li & 31;
        uint4 v = {0u, 0u, 0u, 0u};
        if (nodes[i] >= 0) v = *(const uint4*)(out1 + (size_t)nodes[i] * 8);
        *(uint4*)(H0 + HIDX(r, j)) = v;
    }
    __syncthreads();
    dense_layer(H0, H1, W, WB2 + 65536  + woff, 4096, b0, nt, l31, lh);
    __syncthreads();
    dense_layer(H1, H0, W, WB2 + 131072 + woff, 4096, b1, nt, l31, lh);
    __syncthreads();
    dense_layer(H0, H1, W, WB23 + l31 * 16 + lh * 8, 512, b2, nt, l31, lh);
    __syncthreads();
    f32x16 acc = final_dense(H1, W, wave, l31, lh);

    if (wave < 2) {
        const int row_g = blk * 64 + wave * 32 + l31;
        if (row_g < NROWS && lh == 0)
            out[row_g] = fast_sigmoid(acc[0] + b3[0]);
    }
}

// Build all bf16 blocked weight layouts in workspace (once per launch).
__global__ void transform_kernel(
    const float* __restrict__ w10, const float* __restrict__ w11, const float* __restrict__ w12,
    const float* __restrict__ w13, const float* __restrict__ w20, const float* __restrict__ w21,
    const float* __restrict__ w22, const float* __restrict__ w23, u16* __restrict__ ws) {
    const int id = blockIdx.x * 256 + threadIdx.x;   // 409600 outputs
    float val;
    if (id < 196608) {                         // WB1: 3 layers [8][2][256][16]
        int layer = id >> 16, rem = id & 65535;
        int c = rem >> 13, s = (rem >> 12) & 1, n = (rem >> 4) & 255, kl = rem & 15;
        int k = c * 32 + s * 16 + kl;
        const float* w = layer == 0 ? w10 : (layer == 1 ? w11 : w12);
        val = w[k * 256 + n];
    } else if (id < 204800) {                  // WB13: [8][2][32][16], n>=5 zero
        int rem = id - 196608;
        int c = rem >> 10, s = (rem >> 9) & 1, n = (rem >> 4) & 31, kl = rem & 15;
        int k = c * 32 + s * 16 + kl;
        val = (n < 5) ? w13[k * 5 + n] : 0.0f;
    } else if (id < 401408) {                  // WB2: 3 layers; layer0 K 160->256 expanded
        int rem = id - 204800;
        int layer = rem >> 16; rem &= 65535;
        int c = rem >> 13, s = (rem >> 12) & 1, n = (rem >> 4) & 255, kl = rem & 15;
        int k = c * 32 + s * 16 + kl;
        if (layer == 0) {
            int j = k >> 3, v = k & 7;
            val = (v < 5) ? w20[(j * 5 + v) * 256 + n] : 0.0f;
        } else {
            val = (layer == 1 ? w21 : w22)[k * 256 + n];
        }
    } else {                                   // WB23: [8][2][32][16], n!=0 zero
        int rem = id - 401408;
        int c = rem >> 10, s = (rem >> 9) & 1, n = (rem >> 4) & 31, kl = rem & 15;
        int k = c * 32 + s * 16 + kl;
        val = (n == 0) ? w23[k] : 0.0f;
    }
    u32 u = __builtin_bit_cast(u32, val);
    u = (u + 0x7FFFu + ((u >> 16) & 1u)) >> 16;
    ws[id] = (u16)u;
}

extern "C" void kernel_launch(void* const* d_in, const int* in_sizes, int n_in,
                              void* d_out, int out_size, void* d_ws, size_t ws_size,
                              hipStream_t stream) {
    const int*   ei  = (const int*)d_in[1];     // edge_index [2][E] int32
    const float* ea  = (const float*)d_in[2];   // edge_attr [E][8] f32
    const float* w10 = (const float*)d_in[3];  const float* b10 = (const float*)d_in[4];
    const float* w11 = (const float*)d_in[5];  const float* b11 = (const float*)d_in[6];
    const float* w12 = (const float*)d_in[7];  const float* b12 = (const float*)d_in[8];
    const float* w13 = (const float*)d_in[9];  const float* b13 = (const float*)d_in[10];
    const float* w20 = (const float*)d_in[11]; const float* b20 = (const float*)d_in[12];
    const float* w21 = (const float*)d_in[13]; const float* b21 = (const float*)d_in[14];
    const float* w22 = (const float*)d_in[15]; const float* b22 = (const float*)d_in[16];
    const float* w23 = (const float*)d_in[17]; const float* b23 = (const float*)d_in[18];

    u16* ws   = (u16*)d_ws;            // u16-unit offsets
    u16* WB1  = ws;                    // 196608
    u16* WB13 = ws + 196608;           // 8192
    u16* WB2  = ws + 204800;           // 196608
    u16* WB23 = ws + 401408;           // 8192
    u16* out1 = ws + 409600;           // 100000 x 8 bf16 (padded rows)

    hipLaunchKernelGGL(transform_kernel, dim3(1600), dim3(256), 0, stream,
                       w10, w11, w12, w13, w20, w21, w22, w23, ws);
    hipLaunchKernelGGL(mlp1_kernel, dim3(1563), dim3(512), 0, stream,
                       ea, WB1, WB13, b10, b11, b12, b13, out1);
    hipLaunchKernelGGL(mlp2_kernel, dim3(1563), dim3(512), 0, stream,
                       ei + E_EDGES, out1, WB2, WB23, b20, b21, b22, b23, (float*)d_out);
}

// Round 6
// 332.929 us; speedup vs baseline: 1.2181x; 1.0938x over previous
//
#include <hip/hip_runtime.h>
#include <stdint.h>

typedef uint16_t u16;
typedef uint32_t u32;
typedef __attribute__((ext_vector_type(8)))  __bf16 bf16x8;
typedef __attribute__((ext_vector_type(16))) float  f32x16;

#define NROWS   100000
#define E_EDGES 3200000

// LDS activation tile: H[64 rows][256 cols] bf16, XOR-swizzled on 8-elem (16B)
// granules: elem offset = row*256 + ((g ^ (row&31))<<3) + e   (g = col>>3)
#define HIDX(r, g) (((r) << 8) + ((((g) ^ ((r) & 31))) << 3))

#define MFMA(a, b, c) __builtin_amdgcn_mfma_f32_32x32x16_bf16((a), (b), (c), 0, 0, 0)

__device__ __forceinline__ u32 pk2(float a, float b) {   // manual RNE bf16 pack
    u32 ua = __builtin_bit_cast(u32, a), ub = __builtin_bit_cast(u32, b);
    ua = (ua + 0x7FFFu + ((ua >> 16) & 1u)) >> 16;
    ub = (ub + 0x7FFFu + ((ub >> 16) & 1u)) >> 16;
    return ua | (ub << 16);
}
// tanh(x) = 1 - 2/(exp2(x*2*log2e)+1): mul, exp2, add, rcp, fma
__device__ __forceinline__ float fast_tanh(float x) {
    float e = __builtin_amdgcn_exp2f(x * 2.885390081777927f);
    float r = __builtin_amdgcn_rcpf(e + 1.0f);
    return __builtin_fmaf(-2.0f, r, 1.0f);
}
__device__ __forceinline__ float fast_sigmoid(float x) {
    float e = __builtin_amdgcn_exp2f(x * -1.4426950408889634f);
    return __builtin_amdgcn_rcpf(1.0f + e);
}

// One 256->256 layer + bias + tanh, in place on Hs (64 rows).
// 4 waves/block; wave owns n-tiles {2w, 2w+1} x batch-tiles {0,1}: acc[4] (64 AGPR).
// Weights stream from L2 per step, software-pipelined one step ahead together
// with the H fragments (covers L2 ~200cyc / LDS ~120cyc latency with 4 MFMAs).
// WB layout: [step 16][n 256][kloc 16] bf16 (k = s*16 + kloc), step stride 4096.
__device__ __forceinline__ void dense256(u16* __restrict__ Hs, const u16* __restrict__ WB,
                                         const float* __restrict__ bias,
                                         int wave, int l31, int lh) {
    f32x16 acc[4];
#pragma unroll
    for (int i = 0; i < 4; ++i)
#pragma unroll
        for (int j = 0; j < 16; ++j) acc[i][j] = 0.0f;

    __syncthreads();   // H writes from previous phase visible

    const u16* wp = WB + (wave * 64 + l31) * 16 + lh * 8;   // n-tile 2w; +512 -> 2w+1
    bf16x8 w0 = *(const bf16x8*)(wp);
    bf16x8 w1 = *(const bf16x8*)(wp + 512);
    bf16x8 h0 = *(const bf16x8*)(Hs + HIDX(l31, lh));
    bf16x8 h1 = *(const bf16x8*)(Hs + HIDX(32 + l31, lh));

#pragma unroll
    for (int s = 0; s < 16; ++s) {
        bf16x8 nw0 = w0, nw1 = w1, nh0 = h0, nh1 = h1;
        if (s < 15) {
            const int ng = 2 * (s + 1) + lh;
            nw0 = *(const bf16x8*)(wp + (s + 1) * 4096);
            nw1 = *(const bf16x8*)(wp + (s + 1) * 4096 + 512);
            nh0 = *(const bf16x8*)(Hs + HIDX(l31, ng));
            nh1 = *(const bf16x8*)(Hs + HIDX(32 + l31, ng));
        }
        acc[0] = MFMA(w0, h0, acc[0]);
        acc[1] = MFMA(w0, h1, acc[1]);
        acc[2] = MFMA(w1, h0, acc[2]);
        acc[3] = MFMA(w1, h1, acc[3]);
        w0 = nw0; w1 = nw1; h0 = nh0; h1 = nh1;
    }
    __syncthreads();   // all H reads done before in-place overwrite

    // epilogue: bias + tanh + packed write-back (4 consecutive neurons per reg-quad)
#pragma unroll
    for (int i = 0; i < 2; ++i) {
        const int nt = wave * 2 + i;
#pragma unroll
        for (int rg = 0; rg < 4; ++rg) {
            const float4 bv = *(const float4*)(bias + nt * 32 + rg * 8 + lh * 4);
#pragma unroll
            for (int b = 0; b < 2; ++b) {
                const f32x16& A = acc[i * 2 + b];
                float x0 = fast_tanh(A[rg * 4 + 0] + bv.x);
                float x1 = fast_tanh(A[rg * 4 + 1] + bv.y);
                float x2 = fast_tanh(A[rg * 4 + 2] + bv.z);
                float x3 = fast_tanh(A[rg * 4 + 3] + bv.w);
                const int r = b * 32 + l31;              // batch row (C/D col)
                const int g = nt * 4 + rg;               // neuron granule
                uint2 v; v.x = pk2(x0, x1); v.y = pk2(x2, x3);
                *(uint2*)(Hs + (r << 8) + (((g) ^ (r & 31)) << 3) + lh * 4) = v;
            }
        }
    }
}

// final 256->32(padded) layer; waves 0..1 each take one 32-row batch tile.
// WBf layout: [step 16][n 32][kloc 16], step stride 512.
__device__ __forceinline__ f32x16 final_dense(const u16* __restrict__ Hs,
                                              const u16* __restrict__ WBf,
                                              int wave, int l31, int lh) {
    __syncthreads();   // H ready
    f32x16 acc;
#pragma unroll
    for (int j = 0; j < 16; ++j) acc[j] = 0.0f;
    if (wave < 2) {
        const u16* wp = WBf + l31 * 16 + lh * 8;
        bf16x8 w = *(const bf16x8*)(wp);
        bf16x8 h = *(const bf16x8*)(Hs + HIDX(wave * 32 + l31, lh));
#pragma unroll
        for (int s = 0; s < 16; ++s) {
            bf16x8 nw = w, nh = h;
            if (s < 15) {
                nw = *(const bf16x8*)(wp + (s + 1) * 512);
                nh = *(const bf16x8*)(Hs + HIDX(wave * 32 + l31, 2 * (s + 1) + lh));
            }
            acc = MFMA(w, h, acc);
            w = nw; h = nh;
        }
    }
    return acc;
}

__global__ __launch_bounds__(256, 4) void mlp1_kernel(
    const float* __restrict__ ea, const u16* __restrict__ WB1, const u16* __restrict__ WB13,
    const float* __restrict__ b0, const float* __restrict__ b1, const float* __restrict__ b2,
    const float* __restrict__ b3, u16* __restrict__ out1) {
    __shared__ u16 Hs[64 * 256];   // 32 KB -> 4 blocks/CU (128 KB), phase-decorrelated
    const int tid = threadIdx.x, wave = tid >> 6, lane = tid & 63, blk = blockIdx.x;
    const int l31 = lane & 31, lh = lane >> 5;

    // stage A = edge_attr rows: coalesced 32B/lane, cvt to bf16 (zero-pad tail)
#pragma unroll
    for (int i = 0; i < 8; ++i) {
        const int li = i * 256 + tid;           // 0..2047 granule tasks
        const int r = li >> 5, g = li & 31;
        const int rg_ = blk * 64 + r;
        uint4 v = {0u, 0u, 0u, 0u};
        if (rg_ < NROWS) {
            const float* p = ea + (size_t)rg_ * 256 + g * 8;
            float4 a0 = *(const float4*)p;
            float4 a1 = *(const float4*)(p + 4);
            v.x = pk2(a0.x, a0.y); v.y = pk2(a0.z, a0.w);
            v.z = pk2(a1.x, a1.y); v.w = pk2(a1.z, a1.w);
        }
        *(uint4*)(Hs + HIDX(r, g)) = v;
    }
    dense256(Hs, WB1,          b0, wave, l31, lh);
    dense256(Hs, WB1 + 65536,  b1, wave, l31, lh);
    dense256(Hs, WB1 + 131072, b2, wave, l31, lh);
    f32x16 acc = final_dense(Hs, WB13, wave, l31, lh);

    if (wave < 2) {
        const int row_g = blk * 64 + wave * 32 + l31;
        if (row_g < NROWS) {
            if (lh == 0) {           // neurons 0..3 in regs 0..3
                float s0 = fast_sigmoid(acc[0] + b3[0]);
                float s1 = fast_sigmoid(acc[1] + b3[1]);
                float s2 = fast_sigmoid(acc[2] + b3[2]);
                float s3 = fast_sigmoid(acc[3] + b3[3]);
                uint2 v; v.x = pk2(s0, s1); v.y = pk2(s2, s3);
                *(uint2*)(out1 + (size_t)row_g * 8) = v;
            } else {                 // neuron 4 in reg 0; zero-pad 5..7
                float s4 = fast_sigmoid(acc[0] + b3[4]);
                uint2 v; v.x = pk2(s4, 0.0f); v.y = 0u;
                *(uint2*)(out1 + (size_t)row_g * 8 + 4) = v;
            }
        }
    }
}

__global__ __launch_bounds__(256, 4) void mlp2_kernel(
    const int* __restrict__ idx1, const u16* __restrict__ out1,
    const u16* __restrict__ WB2, const u16* __restrict__ WB23,
    const float* __restrict__ b0, const float* __restrict__ b1, const float* __restrict__ b2,
    const float* __restrict__ b3, float* __restrict__ out) {
    __shared__ u16 Hs[64 * 256];
    const int tid = threadIdx.x, wave = tid >> 6, lane = tid & 63, blk = blockIdx.x;
    const int l31 = lane & 31, lh = lane >> 5;

    // gather: 2048 edges/block; prefetch indices then keep 8 gathers in flight
    int nodes[8];
#pragma unroll
    for (int i = 0; i < 8; ++i) {
        const long e = (long)blk * 2048 + i * 256 + tid;
        nodes[i] = (e < (long)E_EDGES) ? idx1[e] : -1;
    }
#pragma unroll
    for (int i = 0; i < 8; ++i) {
        const int li = i * 256 + tid;           // 0..2047
        const int r = li >> 5, j = li & 31;
        uint4 v = {0u, 0u, 0u, 0u};
        if (nodes[i] >= 0) v = *(const uint4*)(out1 + (size_t)nodes[i] * 8);
        *(uint4*)(Hs + HIDX(r, j)) = v;
    }
    dense256(Hs, WB2,          b0, wave, l31, lh);   // K padded 160->256, zero weights
    dense256(Hs, WB2 + 65536,  b1, wave, l31, lh);
    dense256(Hs, WB2 + 131072, b2, wave, l31, lh);
    f32x16 acc = final_dense(Hs, WB23, wave, l31, lh);

    if (wave < 2) {
        const int row_g = blk * 64 + wave * 32 + l31;
        if (row_g < NROWS && lh == 0)
            out[row_g] = fast_sigmoid(acc[0] + b3[0]);
    }
}

// Build all bf16 blocked weight layouts in workspace (once per launch).
// Layouts: WB [step 16][n N][kloc 16], k = step*16 + kloc.
__global__ void transform_kernel(
    const float* __restrict__ w10, const float* __restrict__ w11, const float* __restrict__ w12,
    const float* __restrict__ w13, const float* __restrict__ w20, const float* __restrict__ w21,
    const float* __restrict__ w22, const float* __restrict__ w23, u16* __restrict__ ws) {
    const int id = blockIdx.x * 256 + threadIdx.x;   // 409600 outputs
    float val;
    if (id < 196608) {                         // WB1: 3 layers [16][256][16]
        int layer = id >> 16, rem = id & 65535;
        int s = rem >> 12, n = (rem >> 4) & 255, kl = rem & 15;
        int k = s * 16 + kl;
        const float* w = layer == 0 ? w10 : (layer == 1 ? w11 : w12);
        val = w[k * 256 + n];
    } else if (id < 204800) {                  // WB13: [16][32][16], n>=5 zero
        int rem = id - 196608;
        int s = rem >> 9, n = (rem >> 4) & 31, kl = rem & 15;
        int k = s * 16 + kl;
        val = (n < 5) ? w13[k * 5 + n] : 0.0f;
    } else if (id < 401408) {                  // WB2: 3 layers; layer0 K 160->256 expanded
        int rem = id - 204800;
        int layer = rem >> 16; rem &= 65535;
        int s = rem >> 12, n = (rem >> 4) & 255, kl = rem & 15;
        int k = s * 16 + kl;
        if (layer == 0) {
            int j = k >> 3, v = k & 7;
            val = (v < 5) ? w20[(j * 5 + v) * 256 + n] : 0.0f;
        } else {
            val = (layer == 1 ? w21 : w22)[k * 256 + n];
        }
    } else {                                   // WB23: [16][32][16], n!=0 zero
        int rem = id - 401408;
        int s = rem >> 9, n = (rem >> 4) & 31, kl = rem & 15;
        int k = s * 16 + kl;
        val = (n == 0) ? w23[k] : 0.0f;
    }
    u32 u = __builtin_bit_cast(u32, val);
    u = (u + 0x7FFFu + ((u >> 16) & 1u)) >> 16;   // RNE
    ws[id] = (u16)u;
}

extern "C" void kernel_launch(void* const* d_in, const int* in_sizes, int n_in,
                              void* d_out, int out_size, void* d_ws, size_t ws_size,
                              hipStream_t stream) {
    const int*   ei  = (const int*)d_in[1];     // edge_index [2][E] int32
    const float* ea  = (const float*)d_in[2];   // edge_attr [E][8] f32
    const float* w10 = (const float*)d_in[3];  const float* b10 = (const float*)d_in[4];
    const float* w11 = (const float*)d_in[5];  const float* b11 = (const float*)d_in[6];
    const float* w12 = (const float*)d_in[7];  const float* b12 = (const float*)d_in[8];
    const float* w13 = (const float*)d_in[9];  const float* b13 = (const float*)d_in[10];
    const float* w20 = (const float*)d_in[11]; const float* b20 = (const float*)d_in[12];
    const float* w21 = (const float*)d_in[13]; const float* b21 = (const float*)d_in[14];
    const float* w22 = (const float*)d_in[15]; const float* b22 = (const float*)d_in[16];
    const float* w23 = (const float*)d_in[17]; const float* b23 = (const float*)d_in[18];

    u16* ws   = (u16*)d_ws;            // u16-unit offsets
    u16* WB1  = ws;                    // 196608
    u16* WB13 = ws + 196608;           // 8192
    u16* WB2  = ws + 204800;           // 196608
    u16* WB23 = ws + 401408;           // 8192
    u16* out1 = ws + 409600;           // 100000 x 8 bf16 (padded rows)

    hipLaunchKernelGGL(transform_kernel, dim3(1600), dim3(256), 0, stream,
                       w10, w11, w12, w13, w20, w21, w22, w23, ws);
    hipLaunchKernelGGL(mlp1_kernel, dim3(1563), dim3(256), 0, stream,
                       ea, WB1, WB13, b10, b11, b12, b13, out1);
    hipLaunchKernelGGL(mlp2_kernel, dim3(1563), dim3(256), 0, stream,
                       ei + E_EDGES, out1, WB2, WB23, b20, b21, b22, b23, (float*)d_out);
}